// Round 1
// baseline (8776.743 us; speedup 1.0000x reference)
//
#include <hip/hip_runtime.h>
#include <hip/hip_bf16.h>

#define BATCH 256
#define SEQT  256
#define INDIM 256
#define UNITS 512
#define GCOLS 2048
#define NWGS  256
#define BLOCKT 256

typedef __attribute__((ext_vector_type(8))) __bf16 bf16x8;
typedef __attribute__((ext_vector_type(4))) float  f32x4;

#define AS1 __attribute__((address_space(1)))
#define AS3 __attribute__((address_space(3)))

// async global -> LDS, 16B per lane; LDS dest = base + laneid*16 (wave-uniform base)
__device__ __forceinline__ void load_lds16(const void* gsrc, void* ldst) {
    __builtin_amdgcn_global_load_lds((AS1 void*)gsrc, (AS3 void*)ldst, 16, 0, 0);
}

__device__ __forceinline__ float sigf(float x) { return 1.0f / (1.0f + __expf(-x)); }

__device__ __forceinline__ float tanhfast(float x) {
    float e = __expf(-2.0f * fabsf(x));
    float t = (1.0f - e) / (1.0f + e);
    return x < 0.0f ? -t : t;
}

__device__ __forceinline__ unsigned short f2bf(float f) {
    unsigned u = __float_as_uint(f);
    u += 0x7fffu + ((u >> 16) & 1u);   // RNE
    return (unsigned short)(u >> 16);
}

// Monotonic-counter grid barrier: release fence -> arrive -> relaxed poll -> acquire fence.
__device__ __forceinline__ void grid_barrier(unsigned* cnt, unsigned target) {
    __syncthreads();
    if (threadIdx.x == 0) {
        __threadfence();  // release: push h writes (L2 -> LLC)
        __hip_atomic_fetch_add(cnt, 1u, __ATOMIC_RELAXED, __HIP_MEMORY_SCOPE_AGENT);
        while (__hip_atomic_load(cnt, __ATOMIC_RELAXED, __HIP_MEMORY_SCOPE_AGENT) < target)
            __builtin_amdgcn_s_sleep(1);
        __threadfence();  // acquire: invalidate L1/L2 so fresh h is visible
    }
    __syncthreads();
}

// One WG owns a 64-row x (4 gates x 16 units) tile of one layer's z.
// LAYER 0: K = 768  (256 x | 512 h0),  NKK=24, B = [W0;U0]
// LAYER 1: K = 1024 (512 h0 | 512 h1), NKK=32, B = [W1;U1]
// A is staged in LDS in MFMA-fragment order: frag f=(kk*4+m) occupies 1024B; lane slot = lane*16.
template <int LAYER>
__device__ void run_lstm(const float* __restrict__ X,
                         const float* __restrict__ Wx, const float* __restrict__ Ux,
                         const float* __restrict__ bias_v,
                         const float* __restrict__ Wfc, const float* __restrict__ bfc,
                         float* __restrict__ out, unsigned* __restrict__ counter,
                         unsigned short* __restrict__ h0buf,
                         unsigned short* __restrict__ h1buf,
                         unsigned char* smem)
{
    constexpr int NKK = LAYER ? 32 : 24;   // K / 32
    constexpr int KS  = LAYER ? 16 : 8;    // kk where B switches Wx -> Ux

    const int tid  = threadIdx.x;
    const int lane = tid & 63;
    const int w    = tid >> 6;                       // wave id = gate id (i,f,g,o)
    const int lwg  = LAYER ? (int)blockIdx.x - 128 : (int)blockIdx.x;
    const int r0   = (lwg >> 5) * 64;                // batch-row base
    const int u0   = (lwg & 31) * 16;                // unit-slice base
    const int l16  = lane & 15;
    const int kb8  = (lane >> 4) * 8;
    const int col  = w * 512 + u0 + l16;             // this lane's z-column
    float* gates   = (float*)(smem + 131072);        // [4][64][17] f32

    // ---- load B fragments into registers (once; weights stay resident all 257 steps) ----
    bf16x8 bfrag[NKK];
#pragma unroll
    for (int kk = 0; kk < NKK; ++kk) {
        const float* srcm = (kk < KS)
            ? (Wx + (size_t)(kk * 32 + kb8) * GCOLS + col)
            : (Ux + (size_t)((kk - KS) * 32 + kb8) * GCOLS + col);
        bf16x8 v;
#pragma unroll
        for (int j = 0; j < 8; ++j) v[j] = (__bf16)srcm[(size_t)j * GCOLS];
        bfrag[kk] = v;
    }
    const float bias = bias_v[col];

    float c[4]  = {0.f, 0.f, 0.f, 0.f};
    float hn[4] = {0.f, 0.f, 0.f, 0.f};
    const int rl = tid & 63;           // cell-phase row-local
    const int jb = (tid >> 6) * 4;     // cell-phase unit-local base

#pragma unroll 1
    for (int s = 0; s <= SEQT; ++s) {
        const bool active = LAYER ? (s >= 1) : (s < SEQT);
        if (active) {
            const int rbuf = (s - 1) & 1, wbuf = s & 1;
            const unsigned short* h0r = h0buf + (size_t)rbuf * BATCH * UNITS;

            // ---- stage A tile (fragment-ordered) ----
            if (LAYER == 0) {
                // x-part: kk 0..7 (fp32 -> bf16 through regs), 8 frags/wave
#pragma unroll
                for (int i = 0; i < 8; ++i) {
                    int f = w * 8 + i;
                    int m = f & 3, kk = f >> 2;
                    int row = r0 + m * 16 + l16;
                    const float* sx = X + ((size_t)row * SEQT + s) * INDIM + kk * 32 + kb8;
                    float4 x0 = *(const float4*)sx;
                    float4 x1 = *(const float4*)(sx + 4);
                    bf16x8 v;
                    v[0] = (__bf16)x0.x; v[1] = (__bf16)x0.y; v[2] = (__bf16)x0.z; v[3] = (__bf16)x0.w;
                    v[4] = (__bf16)x1.x; v[5] = (__bf16)x1.y; v[6] = (__bf16)x1.z; v[7] = (__bf16)x1.w;
                    *(bf16x8*)(smem + (size_t)f * 1024 + lane * 16) = v;
                }
                // h0-part: kk 8..23 via global_load_lds, 16 frags/wave
#pragma unroll
                for (int i = 0; i < 16; ++i) {
                    int f = 32 + w * 16 + i;
                    int m = f & 3, kk = f >> 2;
                    int row = r0 + m * 16 + l16;
                    load_lds16(h0r + (size_t)row * UNITS + (kk - 8) * 32 + kb8,
                               smem + (size_t)f * 1024);
                }
            } else {
                const unsigned short* h1r = h1buf + (size_t)rbuf * BATCH * UNITS;
#pragma unroll
                for (int i = 0; i < 32; ++i) {
                    int f = w * 32 + i;
                    int m = f & 3, kk = f >> 2;
                    int row = r0 + m * 16 + l16;
                    int k = kk * 32 + kb8;
                    const unsigned short* src = (k < 512)
                        ? (h0r + (size_t)row * UNITS + k)
                        : (h1r + (size_t)row * UNITS + (k - 512));
                    load_lds16(src, smem + (size_t)f * 1024);
                }
            }
            __syncthreads();  // drains vmcnt (global_load_lds) + lgkm (ds_write)

            // ---- K-loop: 16x16x32 bf16 MFMA, B from registers, A from LDS ----
            f32x4 acc[4];
#pragma unroll
            for (int m = 0; m < 4; ++m) acc[m] = (f32x4){bias, bias, bias, bias};
#pragma unroll
            for (int kk = 0; kk < NKK; ++kk) {
#pragma unroll
                for (int m = 0; m < 4; ++m) {
                    bf16x8 a = *(const bf16x8*)(smem + (size_t)(kk * 4 + m) * 1024 + lane * 16);
                    acc[m] = __builtin_amdgcn_mfma_f32_16x16x32_bf16(a, bfrag[kk], acc[m], 0, 0, 0);
                }
            }

            // ---- gate exchange: D[(lane>>4)*4+r][lane&15] -> gates[w][rl][ul] (stride 17: conflict-free) ----
#pragma unroll
            for (int m = 0; m < 4; ++m)
#pragma unroll
                for (int r = 0; r < 4; ++r)
                    gates[(w * 64 + m * 16 + (lane >> 4) * 4 + r) * 17 + l16] = acc[m][r];
            __syncthreads();

            // ---- cell: c in registers, h -> bf16 -> global double-buffer ----
            unsigned short hb[4];
#pragma unroll
            for (int j = 0; j < 4; ++j) {
                int ul = jb + j;
                float zi = gates[(0 * 64 + rl) * 17 + ul];
                float zf = gates[(1 * 64 + rl) * 17 + ul];
                float zg = gates[(2 * 64 + rl) * 17 + ul];
                float zo = gates[(3 * 64 + rl) * 17 + ul];
                float cn = sigf(zf) * c[j] + sigf(zi) * tanhfast(zg);
                float h  = sigf(zo) * tanhfast(cn);
                c[j] = cn; hn[j] = h; hb[j] = f2bf(h);
            }
            if (!(LAYER == 1 && s == SEQT)) {
                unsigned short* hw = (LAYER ? h1buf : h0buf)
                    + (size_t)wbuf * BATCH * UNITS + (size_t)(r0 + rl) * UNITS + u0 + jb;
                ushort4 hv; hv.x = hb[0]; hv.y = hb[1]; hv.z = hb[2]; hv.w = hb[3];
                *(ushort4*)hw = hv;
            }
        }
        if (s < SEQT) grid_barrier(counter, (unsigned)NWGS * (unsigned)(s + 1));
    }

    // ---- Dense(1) head from register-resident final h1 ----
    if (LAYER == 1) {
        float p = hn[0] * Wfc[u0 + jb + 0] + hn[1] * Wfc[u0 + jb + 1]
                + hn[2] * Wfc[u0 + jb + 2] + hn[3] * Wfc[u0 + jb + 3];
        if (u0 == 0 && jb == 0) p += bfc[0];
        atomicAdd(out + r0 + rl, p);
    }
}

__global__ void __launch_bounds__(BLOCKT, 1)
lstm_kernel(const float* __restrict__ X,
            const float* __restrict__ W0, const float* __restrict__ U0, const float* __restrict__ b0,
            const float* __restrict__ W1, const float* __restrict__ U1, const float* __restrict__ b1,
            const float* __restrict__ Wfc, const float* __restrict__ bfc,
            float* __restrict__ out, unsigned* __restrict__ counter,
            unsigned short* __restrict__ h0buf, unsigned short* __restrict__ h1buf)
{
    // A frags 128 KiB + gates 17 KiB = 145 KiB (1 WG/CU on gfx950's 160 KiB LDS)
    __shared__ __align__(16) unsigned char smem[148480];
    if (blockIdx.x < 128)
        run_lstm<0>(X, W0, U0, b0, Wfc, bfc, out, counter, h0buf, h1buf, smem);
    else
        run_lstm<1>(X, W1, U1, b1, Wfc, bfc, out, counter, h0buf, h1buf, smem);
}

extern "C" void kernel_launch(void* const* d_in, const int* in_sizes, int n_in,
                              void* d_out, int out_size, void* d_ws, size_t ws_size,
                              hipStream_t stream) {
    (void)in_sizes; (void)n_in; (void)out_size; (void)ws_size;
    const float* X   = (const float*)d_in[0];
    const float* W0  = (const float*)d_in[1];
    const float* U0  = (const float*)d_in[2];
    const float* b0  = (const float*)d_in[3];
    const float* W1  = (const float*)d_in[4];
    const float* U1  = (const float*)d_in[5];
    const float* b1  = (const float*)d_in[6];
    const float* Wfc = (const float*)d_in[7];
    const float* bfc = (const float*)d_in[8];
    float* out = (float*)d_out;

    unsigned char* ws = (unsigned char*)d_ws;
    unsigned* counter      = (unsigned*)ws;                       // 256 B (monotonic barrier counter)
    unsigned short* h0buf  = (unsigned short*)(ws + 256);         // [2][256][512] bf16
    unsigned short* h1buf  = (unsigned short*)(ws + 256 + 2 * BATCH * UNITS * 2);

    // zero barrier counter + h double-buffers (ws is poisoned 0xAA before every call)
    hipMemsetAsync(d_ws, 0, 256 + 4 * BATCH * UNITS * 2, stream);
    hipMemsetAsync(d_out, 0, BATCH * sizeof(float), stream);      // head accumulates via atomicAdd

    lstm_kernel<<<dim3(NWGS), dim3(BLOCKT), 0, stream>>>(
        X, W0, U0, b0, W1, U1, b1, Wfc, bfc, out, counter, h0buf, h1buf);
}

// Round 2
// 5650.011 us; speedup vs baseline: 1.5534x; 1.5534x over previous
//
#include <hip/hip_runtime.h>
#include <hip/hip_bf16.h>

#define BATCH 256
#define SEQT  256
#define INDIM 256
#define UNITS 512
#define GCOLS 2048
#define NWGS  256
#define BLOCKT 256

typedef __attribute__((ext_vector_type(8))) __bf16 bf16x8;
typedef __attribute__((ext_vector_type(4))) float  f32x4;
typedef __attribute__((ext_vector_type(2))) unsigned long long u64x2;

__device__ __forceinline__ float sigf(float x) { return 1.0f / (1.0f + __expf(-x)); }

__device__ __forceinline__ float tanhfast(float x) {
    float e = __expf(-2.0f * fabsf(x));
    float t = (1.0f - e) / (1.0f + e);
    return x < 0.0f ? -t : t;
}

__device__ __forceinline__ unsigned short f2bf(float f) {
    unsigned u = __float_as_uint(f);
    u += 0x7fffu + ((u >> 16) & 1u);   // RNE
    return (unsigned short)(u >> 16);
}

// Agent-coherent (LLC) access helpers: relaxed atomics at AGENT scope compile to
// sc0+sc1 loads/stores — bypass L1/L2, performed at the LLC coherence point.
// => NO buffer_wbl2 / buffer_inv fences needed anywhere.
__device__ __forceinline__ unsigned long long lds_coh(const unsigned long long* p) {
    return __hip_atomic_load(p, __ATOMIC_RELAXED, __HIP_MEMORY_SCOPE_AGENT);
}
__device__ __forceinline__ void st_coh(unsigned long long* p, unsigned long long v) {
    __hip_atomic_store(p, v, __ATOMIC_RELAXED, __HIP_MEMORY_SCOPE_AGENT);
}

// Fence-free grid barrier: h stores are write-through (sc0 sc1), so vmcnt(0)
// drain (implicit in __syncthreads, made explicit here) == global visibility.
// Counter ops are relaxed agent atomics (execute at LLC). No cache maintenance.
__device__ __forceinline__ void grid_barrier(unsigned* cnt, unsigned target) {
    asm volatile("s_waitcnt vmcnt(0)" ::: "memory");
    __syncthreads();
    if (threadIdx.x == 0) {
        __hip_atomic_fetch_add(cnt, 1u, __ATOMIC_RELAXED, __HIP_MEMORY_SCOPE_AGENT);
        while (__hip_atomic_load(cnt, __ATOMIC_RELAXED, __HIP_MEMORY_SCOPE_AGENT) < target)
            __builtin_amdgcn_s_sleep(2);
    }
    __syncthreads();
}

// One WG owns a 64-row x (4 gates x 16 units) tile of one layer's z.
// LAYER 0: K = 768  (256 x | 512 h0),  NKK=24, B = [W0;U0]
// LAYER 1: K = 1024 (512 h0 | 512 h1), NKK=32, B = [W1;U1]
// A staged in LDS in MFMA-fragment order: frag f=(kk*4+m) occupies 1024B; lane slot = lane*16.
template <int LAYER>
__device__ void run_lstm(const float* __restrict__ X,
                         const float* __restrict__ Wx, const float* __restrict__ Ux,
                         const float* __restrict__ bias_v,
                         const float* __restrict__ Wfc, const float* __restrict__ bfc,
                         float* __restrict__ out, unsigned* __restrict__ counter,
                         unsigned short* __restrict__ h0buf,
                         unsigned short* __restrict__ h1buf,
                         unsigned char* smem)
{
    constexpr int NKK = LAYER ? 32 : 24;   // K / 32
    constexpr int KS  = LAYER ? 16 : 8;    // kk where B switches Wx -> Ux

    const int tid  = threadIdx.x;
    const int lane = tid & 63;
    const int w    = tid >> 6;                       // wave id = gate id (i,f,g,o)
    const int lwg  = LAYER ? (int)blockIdx.x - 128 : (int)blockIdx.x;
    const int r0   = (lwg >> 5) * 64;                // batch-row base
    const int u0   = (lwg & 31) * 16;                // unit-slice base
    const int l16  = lane & 15;
    const int kb8  = (lane >> 4) * 8;
    const int col  = w * 512 + u0 + l16;             // this lane's z-column
    float* gates   = (float*)(smem + 131072);        // [4][64][17] f32

    // ---- load B fragments into registers (once; resident all 257 steps) ----
    bf16x8 bfrag[NKK];
#pragma unroll
    for (int kk = 0; kk < NKK; ++kk) {
        const float* srcm = (kk < KS)
            ? (Wx + (size_t)(kk * 32 + kb8) * GCOLS + col)
            : (Ux + (size_t)((kk - KS) * 32 + kb8) * GCOLS + col);
        bf16x8 v;
#pragma unroll
        for (int j = 0; j < 8; ++j) v[j] = (__bf16)srcm[(size_t)j * GCOLS];
        bfrag[kk] = v;
    }
    const float bias = bias_v[col];

    float c[4]  = {0.f, 0.f, 0.f, 0.f};
    float hn[4] = {0.f, 0.f, 0.f, 0.f};
    const int rl = tid & 63;           // cell-phase row-local
    const int jb = (tid >> 6) * 4;     // cell-phase unit-local base

#pragma unroll 1
    for (int s = 0; s <= SEQT; ++s) {
        const bool active = LAYER ? (s >= 1) : (s < SEQT);
        if (active) {
            const int rbuf = (s - 1) & 1, wbuf = s & 1;
            const unsigned short* h0r = h0buf + (size_t)rbuf * BATCH * UNITS;

            // ---- stage A tile (fragment-ordered) ----
            if (LAYER == 0) {
                // x-part: kk 0..7 (fp32 -> bf16, cached loads — X is immutable), 8 frags/wave
#pragma unroll
                for (int i = 0; i < 8; ++i) {
                    int f = w * 8 + i;
                    int m = f & 3, kk = f >> 2;
                    int row = r0 + m * 16 + l16;
                    const float* sx = X + ((size_t)row * SEQT + s) * INDIM + kk * 32 + kb8;
                    float4 x0 = *(const float4*)sx;
                    float4 x1 = *(const float4*)(sx + 4);
                    bf16x8 v;
                    v[0] = (__bf16)x0.x; v[1] = (__bf16)x0.y; v[2] = (__bf16)x0.z; v[3] = (__bf16)x0.w;
                    v[4] = (__bf16)x1.x; v[5] = (__bf16)x1.y; v[6] = (__bf16)x1.z; v[7] = (__bf16)x1.w;
                    *(bf16x8*)(smem + (size_t)f * 1024 + lane * 16) = v;
                }
                // h0-part: kk 8..23, 16 frags/wave via LLC-coherent loads
                unsigned long long hb[32];
#pragma unroll
                for (int i = 0; i < 16; ++i) {
                    int f = 32 + w * 16 + i;
                    int m = f & 3, kk = f >> 2;
                    int row = r0 + m * 16 + l16;
                    const unsigned long long* sp = (const unsigned long long*)
                        (h0r + (size_t)row * UNITS + (kk - 8) * 32 + kb8);
                    hb[2 * i]     = lds_coh(sp);
                    hb[2 * i + 1] = lds_coh(sp + 1);
                }
#pragma unroll
                for (int i = 0; i < 16; ++i) {
                    int f = 32 + w * 16 + i;
                    u64x2 v; v[0] = hb[2 * i]; v[1] = hb[2 * i + 1];
                    *(u64x2*)(smem + (size_t)f * 1024 + lane * 16) = v;
                }
            } else {
                const unsigned short* h1r = h1buf + (size_t)rbuf * BATCH * UNITS;
                unsigned long long hb[64];
#pragma unroll
                for (int i = 0; i < 32; ++i) {
                    int f = w * 32 + i;
                    int m = f & 3, kk = f >> 2;
                    int row = r0 + m * 16 + l16;
                    int k = kk * 32 + kb8;
                    const unsigned long long* sp = (const unsigned long long*)((k < 512)
                        ? (h0r + (size_t)row * UNITS + k)
                        : (h1r + (size_t)row * UNITS + (k - 512)));
                    hb[2 * i]     = lds_coh(sp);
                    hb[2 * i + 1] = lds_coh(sp + 1);
                }
#pragma unroll
                for (int i = 0; i < 32; ++i) {
                    int f = w * 32 + i;
                    u64x2 v; v[0] = hb[2 * i]; v[1] = hb[2 * i + 1];
                    *(u64x2*)(smem + (size_t)f * 1024 + lane * 16) = v;
                }
            }
            __syncthreads();

            // ---- K-loop: 16x16x32 bf16 MFMA, B from registers, A from LDS ----
            f32x4 acc[4];
#pragma unroll
            for (int m = 0; m < 4; ++m) acc[m] = (f32x4){bias, bias, bias, bias};
#pragma unroll
            for (int kk = 0; kk < NKK; ++kk) {
#pragma unroll
                for (int m = 0; m < 4; ++m) {
                    bf16x8 a = *(const bf16x8*)(smem + (size_t)(kk * 4 + m) * 1024 + lane * 16);
                    acc[m] = __builtin_amdgcn_mfma_f32_16x16x32_bf16(a, bfrag[kk], acc[m], 0, 0, 0);
                }
            }

            // ---- gate exchange: stride 17 (conflict-free) ----
#pragma unroll
            for (int m = 0; m < 4; ++m)
#pragma unroll
                for (int r = 0; r < 4; ++r)
                    gates[(w * 64 + m * 16 + (lane >> 4) * 4 + r) * 17 + l16] = acc[m][r];
            __syncthreads();

            // ---- cell: c in registers, h -> bf16 -> LLC-coherent double-buffer ----
            unsigned short hb4[4];
#pragma unroll
            for (int j = 0; j < 4; ++j) {
                int ul = jb + j;
                float zi = gates[(0 * 64 + rl) * 17 + ul];
                float zf = gates[(1 * 64 + rl) * 17 + ul];
                float zg = gates[(2 * 64 + rl) * 17 + ul];
                float zo = gates[(3 * 64 + rl) * 17 + ul];
                float cn = sigf(zf) * c[j] + sigf(zi) * tanhfast(zg);
                float h  = sigf(zo) * tanhfast(cn);
                c[j] = cn; hn[j] = h; hb4[j] = f2bf(h);
            }
            if (!(LAYER == 1 && s == SEQT)) {
                unsigned short* hw = (LAYER ? h1buf : h0buf)
                    + (size_t)wbuf * BATCH * UNITS + (size_t)(r0 + rl) * UNITS + u0 + jb;
                unsigned long long hv = (unsigned long long)hb4[0]
                                      | ((unsigned long long)hb4[1] << 16)
                                      | ((unsigned long long)hb4[2] << 32)
                                      | ((unsigned long long)hb4[3] << 48);
                st_coh((unsigned long long*)hw, hv);
            }
        }
        if (s < SEQT) grid_barrier(counter, (unsigned)NWGS * (unsigned)(s + 1));
    }

    // ---- Dense(1) head from register-resident final h1 ----
    if (LAYER == 1) {
        float p = hn[0] * Wfc[u0 + jb + 0] + hn[1] * Wfc[u0 + jb + 1]
                + hn[2] * Wfc[u0 + jb + 2] + hn[3] * Wfc[u0 + jb + 3];
        if (u0 == 0 && jb == 0) p += bfc[0];
        atomicAdd(out + r0 + rl, p);
    }
}

__global__ void __launch_bounds__(BLOCKT, 1)
lstm_kernel(const float* __restrict__ X,
            const float* __restrict__ W0, const float* __restrict__ U0, const float* __restrict__ b0,
            const float* __restrict__ W1, const float* __restrict__ U1, const float* __restrict__ b1,
            const float* __restrict__ Wfc, const float* __restrict__ bfc,
            float* __restrict__ out, unsigned* __restrict__ counter,
            unsigned short* __restrict__ h0buf, unsigned short* __restrict__ h1buf)
{
    // A frags 128 KiB + gates 17 KiB = 145 KiB (1 WG/CU on gfx950's 160 KiB LDS)
    __shared__ __align__(16) unsigned char smem[148480];
    if (blockIdx.x < 128)
        run_lstm<0>(X, W0, U0, b0, Wfc, bfc, out, counter, h0buf, h1buf, smem);
    else
        run_lstm<1>(X, W1, U1, b1, Wfc, bfc, out, counter, h0buf, h1buf, smem);
}

extern "C" void kernel_launch(void* const* d_in, const int* in_sizes, int n_in,
                              void* d_out, int out_size, void* d_ws, size_t ws_size,
                              hipStream_t stream) {
    (void)in_sizes; (void)n_in; (void)out_size; (void)ws_size;
    const float* X   = (const float*)d_in[0];
    const float* W0  = (const float*)d_in[1];
    const float* U0  = (const float*)d_in[2];
    const float* b0  = (const float*)d_in[3];
    const float* W1  = (const float*)d_in[4];
    const float* U1  = (const float*)d_in[5];
    const float* b1  = (const float*)d_in[6];
    const float* Wfc = (const float*)d_in[7];
    const float* bfc = (const float*)d_in[8];
    float* out = (float*)d_out;

    unsigned char* ws = (unsigned char*)d_ws;
    unsigned* counter      = (unsigned*)ws;                       // barrier counter
    unsigned short* h0buf  = (unsigned short*)(ws + 256);         // [2][256][512] bf16
    unsigned short* h1buf  = (unsigned short*)(ws + 256 + 2 * BATCH * UNITS * 2);

    hipMemsetAsync(d_ws, 0, 256 + 4 * BATCH * UNITS * 2, stream);
    hipMemsetAsync(d_out, 0, BATCH * sizeof(float), stream);      // head accumulates via atomicAdd

    lstm_kernel<<<dim3(NWGS), dim3(BLOCKT), 0, stream>>>(
        X, W0, U0, b0, W1, U1, b1, Wfc, bfc, out, counter, h0buf, h1buf);
}

// Round 3
// 2760.751 us; speedup vs baseline: 3.1791x; 2.0465x over previous
//
#include <hip/hip_runtime.h>
#include <hip/hip_bf16.h>

#define BATCH 256
#define SEQT  256
#define INDIM 256
#define UNITS 512
#define GCOLS 2048
#define BLOCKT 256

typedef __attribute__((ext_vector_type(8))) __bf16 bf16x8;
typedef __attribute__((ext_vector_type(4))) float  f32x4;

#define AS1 __attribute__((address_space(1)))
#define AS3 __attribute__((address_space(3)))

// LLC-coherent async global->LDS: aux 0x11 = SC0|SC1 (LLVM CPol: SC0=1, SC1=16)
// -> bypasses L1/L2, reads at the device coherence point. 16B/lane, LDS dest =
// wave-uniform base + lane*16.
__device__ __forceinline__ void load_lds16_coh(const void* gsrc, void* ldst) {
    __builtin_amdgcn_global_load_lds((AS1 void*)gsrc, (AS3 void*)ldst, 16, 0, 0x11);
}

__device__ __forceinline__ float sigf(float x) { return 1.0f / (1.0f + __expf(-x)); }

__device__ __forceinline__ float tanhfast(float x) {
    float e = __expf(-2.0f * fabsf(x));
    float t = (1.0f - e) / (1.0f + e);
    return x < 0.0f ? -t : t;
}

__device__ __forceinline__ unsigned short f2bf(float f) {
    unsigned u = __float_as_uint(f);
    u += 0x7fffu + ((u >> 16) & 1u);   // RNE
    return (unsigned short)(u >> 16);
}

// LLC-coherent h store (sc0 sc1 write-through; vmcnt(0) drain => globally visible)
__device__ __forceinline__ void st_coh(unsigned long long* p, unsigned long long v) {
    __hip_atomic_store(p, v, __ATOMIC_RELAXED, __HIP_MEMORY_SCOPE_AGENT);
}

// Fence-free group barrier (64 WGs per r0-group; monotonic counter at LLC).
__device__ __forceinline__ void group_barrier(unsigned* cnt, unsigned target) {
    asm volatile("s_waitcnt vmcnt(0)" ::: "memory");
    __syncthreads();
    if (threadIdx.x == 0) {
        __hip_atomic_fetch_add(cnt, 1u, __ATOMIC_RELAXED, __HIP_MEMORY_SCOPE_AGENT);
        while (__hip_atomic_load(cnt, __ATOMIC_RELAXED, __HIP_MEMORY_SCOPE_AGENT) < target)
            __builtin_amdgcn_s_sleep(1);
    }
    __syncthreads();
}

// One WG owns a 64-row x (4 gates x 16 units) tile of one layer's z.
// LAYER 0: K = 768  (256 x | 512 h0),  NKK=24; LAYER 1: K = 1024 (512 h0 | 512 h1), NKK=32.
// A staged in LDS in MFMA-fragment order: frag f=(kk*4+m) occupies 1024B; lane slot = lane*16.
template <int LAYER>
__device__ void run_lstm(const float* __restrict__ X,
                         const float* __restrict__ Wx, const float* __restrict__ Ux,
                         const float* __restrict__ bias_v,
                         const float* __restrict__ Wfc, const float* __restrict__ bfc,
                         float* __restrict__ out, unsigned* __restrict__ cnt,
                         unsigned short* __restrict__ h0buf,
                         unsigned short* __restrict__ h1buf,
                         unsigned char* smem, int r0, int u0)
{
    constexpr int NKK = LAYER ? 32 : 24;   // K / 32
    constexpr int KS  = LAYER ? 16 : 8;    // kk where B switches Wx -> Ux

    const int tid  = threadIdx.x;
    const int lane = tid & 63;
    const int w    = tid >> 6;                       // wave id = gate id (i,f,g,o)
    const int l16  = lane & 15;
    const int kb8  = (lane >> 4) * 8;
    const int col  = w * 512 + u0 + l16;             // this lane's z-column
    float* gates   = (float*)(smem + 131072);        // [4][64][17] f32

    // ---- load B fragments into registers (once; resident all 257 steps) ----
    bf16x8 bfrag[NKK];
#pragma unroll
    for (int kk = 0; kk < NKK; ++kk) {
        const float* srcm = (kk < KS)
            ? (Wx + (size_t)(kk * 32 + kb8) * GCOLS + col)
            : (Ux + (size_t)((kk - KS) * 32 + kb8) * GCOLS + col);
        bf16x8 v;
#pragma unroll
        for (int j = 0; j < 8; ++j) v[j] = (__bf16)srcm[(size_t)j * GCOLS];
        bfrag[kk] = v;
    }
    const float bias = bias_v[col];

    float c[4]  = {0.f, 0.f, 0.f, 0.f};
    float hn[4] = {0.f, 0.f, 0.f, 0.f};
    const int rl = lane;               // cell-phase row-local
    const int jb = w * 4;              // cell-phase unit-local base

    // stage x(t) tile (frags 0..31) — cached loads, fp32 -> bf16 through regs
    auto stage_x = [&](int t) {
#pragma unroll
        for (int i = 0; i < 8; ++i) {
            int f = w * 8 + i;
            int m = f & 3, kk = f >> 2;
            int row = r0 + m * 16 + l16;
            const float* sx = X + ((size_t)row * SEQT + t) * INDIM + kk * 32 + kb8;
            float4 x0 = *(const float4*)sx;
            float4 x1 = *(const float4*)(sx + 4);
            bf16x8 v;
            v[0] = (__bf16)x0.x; v[1] = (__bf16)x0.y; v[2] = (__bf16)x0.z; v[3] = (__bf16)x0.w;
            v[4] = (__bf16)x1.x; v[5] = (__bf16)x1.y; v[6] = (__bf16)x1.z; v[7] = (__bf16)x1.w;
            *(bf16x8*)(smem + (size_t)f * 1024 + lane * 16) = v;
        }
    };

    if (LAYER == 0) stage_x(0);
    __syncthreads();

#pragma unroll 1
    for (int s = 0; s <= SEQT; ++s) {
        const bool active = LAYER ? (s >= 1) : (s < SEQT);
        if (active) {
            const int rbuf = (s - 1) & 1, wbuf = s & 1;
            const unsigned short* h0r = h0buf + (size_t)rbuf * BATCH * UNITS;

            // ---- issue coherent h-frag loads (all in flight at once; no VGPR round trip) ----
            if (LAYER == 0) {
#pragma unroll
                for (int i = 0; i < 16; ++i) {
                    int f = 32 + w * 16 + i;
                    int m = f & 3, kk = f >> 2;
                    int row = r0 + m * 16 + l16;
                    load_lds16_coh(h0r + (size_t)row * UNITS + (kk - 8) * 32 + kb8,
                                   smem + (size_t)f * 1024);
                }
            } else {
                const unsigned short* h1r = h1buf + (size_t)rbuf * BATCH * UNITS;
#pragma unroll
                for (int i = 0; i < 32; ++i) {
                    int f = w * 32 + i;
                    int m = f & 3, kk = f >> 2;
                    int row = r0 + m * 16 + l16;
                    int k = kk * 32 + kb8;
                    const unsigned short* src = (k < 512)
                        ? (h0r + (size_t)row * UNITS + k)
                        : (h1r + (size_t)row * UNITS + (k - 512));
                    load_lds16_coh(src, smem + (size_t)f * 1024);
                }
            }

            f32x4 acc[4];
#pragma unroll
            for (int m = 0; m < 4; ++m) acc[m] = (f32x4){bias, bias, bias, bias};

            if (LAYER == 0) {
                // x-part MFMAs run while h loads fly (x staged pre-barrier)
#pragma unroll
                for (int kk = 0; kk < 8; ++kk)
#pragma unroll
                    for (int m = 0; m < 4; ++m) {
                        bf16x8 a = *(const bf16x8*)(smem + (size_t)(kk * 4 + m) * 1024 + lane * 16);
                        acc[m] = __builtin_amdgcn_mfma_f32_16x16x32_bf16(a, bfrag[kk], acc[m], 0, 0, 0);
                    }
            }

            asm volatile("s_waitcnt vmcnt(0)" ::: "memory");  // own gll deposits done
            __syncthreads();                                   // everyone's deposits done

            {
                constexpr int K0 = LAYER ? 0 : 8;
#pragma unroll
                for (int kk = K0; kk < NKK; ++kk)
#pragma unroll
                    for (int m = 0; m < 4; ++m) {
                        bf16x8 a = *(const bf16x8*)(smem + (size_t)(kk * 4 + m) * 1024 + lane * 16);
                        acc[m] = __builtin_amdgcn_mfma_f32_16x16x32_bf16(a, bfrag[kk], acc[m], 0, 0, 0);
                    }
            }

            // ---- gate exchange: stride 17 (<=4-way conflicts, tiny) ----
#pragma unroll
            for (int m = 0; m < 4; ++m)
#pragma unroll
                for (int r = 0; r < 4; ++r)
                    gates[(w * 64 + m * 16 + (lane >> 4) * 4 + r) * 17 + l16] = acc[m][r];
            __syncthreads();

            // ---- cell: c in registers, h -> bf16 -> LLC-coherent double-buffer ----
            unsigned short hb4[4];
#pragma unroll
            for (int j = 0; j < 4; ++j) {
                int ul = jb + j;
                float zi = gates[(0 * 64 + rl) * 17 + ul];
                float zf = gates[(1 * 64 + rl) * 17 + ul];
                float zg = gates[(2 * 64 + rl) * 17 + ul];
                float zo = gates[(3 * 64 + rl) * 17 + ul];
                float cn = sigf(zf) * c[j] + sigf(zi) * tanhfast(zg);
                float h  = sigf(zo) * tanhfast(cn);
                c[j] = cn; hn[j] = h; hb4[j] = f2bf(h);
            }
            if (!(LAYER == 1 && s == SEQT)) {
                unsigned short* hw = (LAYER ? h1buf : h0buf)
                    + (size_t)wbuf * BATCH * UNITS + (size_t)(r0 + rl) * UNITS + u0 + jb;
                unsigned long long hv = (unsigned long long)hb4[0]
                                      | ((unsigned long long)hb4[1] << 16)
                                      | ((unsigned long long)hb4[2] << 32)
                                      | ((unsigned long long)hb4[3] << 48);
                st_coh((unsigned long long*)hw, hv);
            }

            // ---- pre-stage next x tile (A frags 0..31 fully consumed before sync2) ----
            if (LAYER == 0 && s + 1 < SEQT) stage_x(s + 1);
        }
        if (s < SEQT) group_barrier(cnt, 64u * (unsigned)(s + 1));
    }

    // ---- Dense(1) head from register-resident final h1 ----
    if (LAYER == 1) {
        float p = hn[0] * Wfc[u0 + jb + 0] + hn[1] * Wfc[u0 + jb + 1]
                + hn[2] * Wfc[u0 + jb + 2] + hn[3] * Wfc[u0 + jb + 3];
        if (u0 == 0 && jb == 0) p += bfc[0];
        atomicAdd(out + r0 + rl, p);
    }
}

__global__ void __launch_bounds__(BLOCKT, 1)
lstm_kernel(const float* __restrict__ X,
            const float* __restrict__ W0, const float* __restrict__ U0, const float* __restrict__ b0,
            const float* __restrict__ W1, const float* __restrict__ U1, const float* __restrict__ b1,
            const float* __restrict__ Wfc, const float* __restrict__ bfc,
            float* __restrict__ out, unsigned* __restrict__ counters,
            unsigned short* __restrict__ h0buf, unsigned short* __restrict__ h1buf)
{
    // A frags 128 KiB + gates 17 KiB = 145 KiB (1 WG/CU on gfx950's 160 KiB LDS)
    __shared__ __align__(16) unsigned char smem[148480];
    // XCD-aware remap: bid = S*8 + G  ->  bid%8 == G  ->  all 32 WGs of group G on one XCD.
    // G 0..3 = layer0 r0-groups, G 4..7 = layer1 r0-groups; S 0..31 = unit slice.
    const int G = (int)blockIdx.x & 7;
    const int S = (int)blockIdx.x >> 3;
    const int r0 = (G & 3) * 64;
    const int u0 = S * 16;
    unsigned* cnt = counters + (G & 3) * 64;   // 4 group counters, 256B apart
    if (G < 4)
        run_lstm<0>(X, W0, U0, b0, Wfc, bfc, out, cnt, h0buf, h1buf, smem, r0, u0);
    else
        run_lstm<1>(X, W1, U1, b1, Wfc, bfc, out, cnt, h0buf, h1buf, smem, r0, u0);
}

extern "C" void kernel_launch(void* const* d_in, const int* in_sizes, int n_in,
                              void* d_out, int out_size, void* d_ws, size_t ws_size,
                              hipStream_t stream) {
    (void)in_sizes; (void)n_in; (void)out_size; (void)ws_size;
    const float* X   = (const float*)d_in[0];
    const float* W0  = (const float*)d_in[1];
    const float* U0  = (const float*)d_in[2];
    const float* b0  = (const float*)d_in[3];
    const float* W1  = (const float*)d_in[4];
    const float* U1  = (const float*)d_in[5];
    const float* b1  = (const float*)d_in[6];
    const float* Wfc = (const float*)d_in[7];
    const float* bfc = (const float*)d_in[8];
    float* out = (float*)d_out;

    unsigned char* ws = (unsigned char*)d_ws;
    unsigned* counters     = (unsigned*)ws;                        // 4 x 256B barrier counters
    unsigned short* h0buf  = (unsigned short*)(ws + 1024);         // [2][256][512] bf16
    unsigned short* h1buf  = (unsigned short*)(ws + 1024 + 2 * BATCH * UNITS * 2);

    hipMemsetAsync(d_ws, 0, 1024 + 4 * BATCH * UNITS * 2, stream);
    hipMemsetAsync(d_out, 0, BATCH * sizeof(float), stream);       // head accumulates via atomicAdd

    lstm_kernel<<<dim3(256), dim3(BLOCKT), 0, stream>>>(
        X, W0, U0, b0, W1, U1, b1, Wfc, bfc, out, counters, h0buf, h1buf);
}